// Round 1
// 1460.647 us; speedup vs baseline: 1.0485x; 1.0485x over previous
//
#include <hip/hip_runtime.h>
#include <math.h>

#define NB 16
#define NSQ 512
#define NMAT (NB*NSQ)   // 8192
#define NF 1024         // 32*32
#define NSWEEP 7        // 6 sweeps FAILS (absmax 0.195); 7 hits the comparison floor.
#define SB 36           // LDS row stride (floats): 144B = multiple of 16 -> b128-aligned rows

// ---------------------------------------------------------------------------
// Kernel A: Cayley maps. C = (I - X)(I + X)^{-1}, X = W - W^T.
// ---------------------------------------------------------------------------
__global__ __launch_bounds__(64) void cayley_kernel(
    const float* __restrict__ qw, const float* __restrict__ kw,
    const float* __restrict__ vw, float* __restrict__ Cout) {
  __shared__ float M[32][33];
  __shared__ float R[32][33];
  __shared__ float fac[32];
  const float* W = (blockIdx.x == 0) ? qw : ((blockIdx.x == 1) ? kw : vw);
  const int t = threadIdx.x;
  for (int idx = t; idx < 1024; idx += 64) {
    int i = idx >> 5, j = idx & 31;
    float xv = W[i*32+j] - W[j*32+i];
    float d = (i == j) ? 1.0f : 0.0f;
    M[i][j] = d - xv;
    R[i][j] = d + xv;
  }
  __syncthreads();
  for (int k = 0; k < 32; ++k) {
    float inv = 1.0f / M[k][k];
    __syncthreads();
    if (t < 32) M[k][t] *= inv; else R[k][t-32] *= inv;
    __syncthreads();
    if (t < 32) fac[t] = M[t][k];
    __syncthreads();
    if (t < 32) {
      float mk = M[k][t];
      for (int i = 0; i < 32; ++i) {
        if (i == k) continue;
        M[i][t] -= fac[i] * mk;
      }
    } else {
      int tc = t - 32;
      float rk = R[k][tc];
      for (int i = 0; i < 32; ++i) {
        if (i == k) continue;
        R[i][tc] -= fac[i] * rk;
      }
    }
    __syncthreads();
  }
  // R = C^T ; store C row-major: C[p][q] = R[q][p]
  for (int idx = t; idx < 1024; idx += 64) {
    int p = idx >> 5, q = idx & 31;
    Cout[blockIdx.x * 1024 + idx] = R[q][p];
  }
}

// ---------------------------------------------------------------------------
// Kernel B: per-matrix sym eigendecomposition (parallel Jacobi, XOR pairing),
// then S = V log(w) V^T (zero diag), then q/k/v = offdiag(C S C^T) + norms.
// R13: ONE wave (64 threads) per matrix. __launch_bounds__(64) -> single-wave
// workgroup -> s_barrier elided from __syncthreads (only the lgkm fence
// remains); the ~500 cross-wave barriers per block vanish. LDS cut to TWO
// buffers (9.4KB vs 14.3KB -> ~16 blocks/CU resident vs ~7): epilogue reads
// the 4KB shared C matrices from global (L1-resident broadcast) so U can
// overwrite the dead Vrow in buf0. Per-element arithmetic identical to the
// 128-thread version (same pi = a&1 parity, same accumulation order).
// [R8/R9 LESSON: 2-buffer LDS epilogues cost registers and LOSE - that was
//  at 128 thr with wsum/barrier coupling; single-wave changes the tradeoff.]
// [R4/R5/R6: fused/two-phase r<=3 variants FAILED - do not revisit.]
// ---------------------------------------------------------------------------
__global__ __launch_bounds__(64) void logm_qkv_kernel(
    const float* __restrict__ x, const float* __restrict__ Cm,
    float* __restrict__ qo, float* __restrict__ ko, float* __restrict__ vo,
    float* __restrict__ q2, float* __restrict__ k2) {
  __shared__ __align__(16) float buf0[32*SB];   // A -> Vrow -> (per w) U
  __shared__ __align__(16) float buf1[32*SB];   // Vt -> T (=offdiag S)
  __shared__ __align__(16) float2 cs[16];
  __shared__ __align__(16) float lw[32];
  const int t = threadIdx.x;
  const int m = blockIdx.x;
  const float* xm = x + (size_t)m * NF;

  // init A = x (stride SB, b128) and Vt = I : 256 float4 tasks, 4/thread
  #pragma unroll
  for (int s = 0; s < 4; ++s) {
    int fi = t + 64*s;               // float4 index 0..255
    int i = fi >> 3, j4 = (fi & 7) << 2;
    float4 xv = *(const float4*)&xm[(size_t)fi*4];
    *(float4*)&buf0[i*SB + j4] = xv;
    float4 iv;
    iv.x = (i == j4+0) ? 1.0f : 0.0f;
    iv.y = (i == j4+1) ? 1.0f : 0.0f;
    iv.z = (i == j4+2) ? 1.0f : 0.0f;
    iv.w = (i == j4+3) ? 1.0f : 0.0f;
    *(float4*)&buf1[i*SB + j4] = iv;
  }
  __syncthreads();

  const int abase = t >> 4;    // row-pair group 0..3
  const int bI = t & 15;       // col-pair index
  const int pi = abase & 1;    // role-swap parity (== a&1 for a = abase+4u)

  for (int sw = 0; sw < NSWEEP; ++sw) {
    for (int r = 1; r < 32; ++r) {
      const int h = 31 - __builtin_clz((unsigned)r);
      const int lowmask = (1 << h) - 1;
      // phase 1: rotation angles for the 16 disjoint pairs {p, p^r}
      if (t < 16) {
        int p = ((t >> h) << (h+1)) | (t & lowmask);
        int q = p ^ r;
        float apq = buf0[p*SB+q];
        float c = 1.0f, s = 0.0f;
        if (fabsf(apq) > 1e-36f) {
          float app = buf0[p*SB+p];
          float aqq = buf0[q*SB+q];
          float tau = (aqq - app) / (2.0f * apq);
          float tt = 1.0f / (fabsf(tau) + sqrtf(1.0f + tau*tau));
          tt = (tau < 0.0f) ? -tt : tt;
          c = 1.0f / sqrtf(1.0f + tt*tt);
          s = tt * c;
        }
        cs[t] = make_float2(c, s);
      }
      __syncthreads();
      if (r == 1) {
        // --- phase A: row rotations B = J^T A (b128); pairs (2k,2k+1);
        //     128 tasks (16 pairs x 8 chunks), 2 per thread ---
        #pragma unroll
        for (int s2 = 0; s2 < 2; ++s2) {
          int tk = t + 64*s2;
          int pr = tk >> 3;                // pair 0..15
          int ch = (tk & 7) << 2;          // column chunk
          int p = pr << 1;                 // h=0 -> p = 2*pr
          int q = p | 1;
          float2 c2 = cs[pr];
          float4 ap = *(float4*)&buf0[p*SB + ch];
          float4 aq = *(float4*)&buf0[q*SB + ch];
          float4 np, nq;
          np.x = c2.x*ap.x - c2.y*aq.x;  nq.x = fmaf(c2.y, ap.x, c2.x*aq.x);
          np.y = c2.x*ap.y - c2.y*aq.y;  nq.y = fmaf(c2.y, ap.y, c2.x*aq.y);
          np.z = c2.x*ap.z - c2.y*aq.z;  nq.z = fmaf(c2.y, ap.z, c2.x*aq.z);
          np.w = c2.x*ap.w - c2.y*aq.w;  nq.w = fmaf(c2.y, ap.w, c2.x*aq.w);
          *(float4*)&buf0[p*SB + ch] = np;
          *(float4*)&buf0[q*SB + ch] = nq;
        }
        __syncthreads();   // r is loop-uniform -> all threads reach this
        // --- phase B: col rotations A' = B J, in-register per row-chunk;
        //     local col pairs (0,1) w/ cs[2c] and (2,3) w/ cs[2c+1];
        //     256 tasks, 4 per thread ---
        #pragma unroll
        for (int s4 = 0; s4 < 4; ++s4) {
          int tsk = t + 64*s4;             // 0..255
          int i = tsk >> 3;                // row 0..31
          int cch = tsk & 7;               // chunk 0..7 (cols 4c..4c+3)
          float2 cA = cs[2*cch];
          float2 cB = cs[2*cch+1];
          float4 y = *(float4*)&buf0[i*SB + 4*cch];
          float4 z;
          z.x = cA.x*y.x - cA.y*y.y;  z.y = fmaf(cA.y, y.x, cA.x*y.y);
          z.z = cB.x*y.z - cB.y*y.w;  z.w = fmaf(cB.y, y.z, cB.x*y.w);
          *(float4*)&buf0[i*SB + 4*cch] = z;
        }
      } else {
        // blocked 2x2 scalar update, pi-swapped; 256 blocks, 4 per thread.
        int pb = ((bI >> h) << (h+1)) | (bI & lowmask);
        int qb = pb ^ r;
        if (pi) { int tmp = pb; pb = qb; qb = tmp; }
        const float2 cb2 = cs[bI];
        const float cbb = cb2.x;
        const float sbb = pi ? -cb2.y : cb2.y;
        #pragma unroll
        for (int u = 0; u < 4; ++u) {
          int a = abase + 4*u;
          int pa = ((a >> h) << (h+1)) | (a & lowmask);
          int qa = pa ^ r;
          if (pi) { int tmp = pa; pa = qa; qa = tmp; }
          float2 ca2 = cs[a];
          float caa = ca2.x;
          float saa = pi ? -ca2.y : ca2.y;
          float* rp = buf0 + pa*SB;
          float* rq = buf0 + qa*SB;
          float x11 = rp[pb], x12 = rp[qb];
          float x21 = rq[pb], x22 = rq[qb];
          float y11 = caa*x11 - saa*x21;
          float y12 = caa*x12 - saa*x22;
          float y21 = fmaf(saa, x11, caa*x21);
          float y22 = fmaf(saa, x12, caa*x22);
          rp[pb] = cbb*y11 - sbb*y12;
          rp[qb] = fmaf(sbb, y11, cbb*y12);
          rq[pb] = cbb*y21 - sbb*y22;
          rq[qb] = fmaf(sbb, y21, cbb*y22);
        }
      }
      // V^T row rotations (Vt = J^T Vt), 128 float4 tasks, 2 per thread
      #pragma unroll
      for (int s2 = 0; s2 < 2; ++s2) {
        int tk = t + 64*s2;
        int pr = tk >> 3;                // pair 0..15
        int ch = (tk & 7) << 2;          // column chunk
        int p = ((pr >> h) << (h+1)) | (pr & lowmask);
        int q = p ^ r;
        float2 c2 = cs[pr];
        float4 vp = *(float4*)&buf1[p*SB + ch];
        float4 vq = *(float4*)&buf1[q*SB + ch];
        float4 np, nq;
        np.x = c2.x*vp.x - c2.y*vq.x;  nq.x = fmaf(c2.y, vp.x, c2.x*vq.x);
        np.y = c2.x*vp.y - c2.y*vq.y;  nq.y = fmaf(c2.y, vp.y, c2.x*vq.y);
        np.z = c2.x*vp.z - c2.y*vq.z;  nq.z = fmaf(c2.y, vp.z, c2.x*vq.z);
        np.w = c2.x*vp.w - c2.y*vq.w;  nq.w = fmaf(c2.y, vp.w, c2.x*vq.w);
        *(float4*)&buf1[p*SB + ch] = np;
        *(float4*)&buf1[q*SB + ch] = nq;
      }
      __syncthreads();
    }
  }

  if (t < 32) lw[t] = logf(fmaxf(buf0[t*SB+t], 1e-30f));
  __syncthreads();
  // transpose Vt(buf1) -> Vrow(buf0): 1024 scalars, 16 per thread
  #pragma unroll
  for (int s = 0; s < 16; ++s) {
    int idx = t + 64*s;
    int i = idx >> 5, k = idx & 31;
    buf0[i*SB + k] = buf1[k*SB + i];
  }
  __syncthreads();

  // tile partition: 64 threads own 4x4 output tiles (8 row-groups x 8 col-groups)
  const int rg = t >> 3, cg = t & 7;
  const int i0 = rg*4, j0 = cg*4;
  // T = offdiag(S), S[i][j] = sum_k (Vrow[i][k]*lw[k]) * Vrow[j][k]  -> buf1
  {
    float acc[4][4] = {};
    #pragma unroll
    for (int k4 = 0; k4 < 32; k4 += 4) {
      float4 lv = *(float4*)&lw[k4];
      float4 av[4], bv[4];
      #pragma unroll
      for (int d = 0; d < 4; ++d) {
        float4 a4 = *(float4*)&buf0[(i0+d)*SB + k4];
        av[d].x = a4.x*lv.x; av[d].y = a4.y*lv.y; av[d].z = a4.z*lv.z; av[d].w = a4.w*lv.w;
      }
      #pragma unroll
      for (int e = 0; e < 4; ++e)
        bv[e] = *(float4*)&buf0[(j0+e)*SB + k4];
      #pragma unroll
      for (int d = 0; d < 4; ++d)
        #pragma unroll
        for (int e = 0; e < 4; ++e) {
          acc[d][e] = fmaf(av[d].x, bv[e].x, acc[d][e]);
          acc[d][e] = fmaf(av[d].y, bv[e].y, acc[d][e]);
          acc[d][e] = fmaf(av[d].z, bv[e].z, acc[d][e]);
          acc[d][e] = fmaf(av[d].w, bv[e].w, acc[d][e]);
        }
    }
    #pragma unroll
    for (int d = 0; d < 4; ++d) {
      #pragma unroll
      for (int e = 0; e < 4; ++e)
        if (i0+d == j0+e) acc[d][e] = 0.0f;
      float4 z4;
      z4.x = acc[d][0]; z4.y = acc[d][1]; z4.z = acc[d][2]; z4.w = acc[d][3];
      *(float4*)&buf1[(i0+d)*SB + j0] = z4;   // Vt dead; T -> buf1
    }
  }
  __syncthreads();

  for (int w = 0; w < 3; ++w) {
    const float* Cw = Cm + w*1024;   // 4KB, broadcast-read by all blocks: L1-resident
    // U = C * T (T symmetric): U[i][j] = sum_k C[i][k] * T[j][k] -> buf0 (Vrow dead)
    {
      float acc[4][4] = {};
      #pragma unroll
      for (int k4 = 0; k4 < 32; k4 += 4) {
        float4 av[4], bv[4];
        #pragma unroll
        for (int d = 0; d < 4; ++d)
          av[d] = *(const float4*)&Cw[(i0+d)*32 + k4];
        #pragma unroll
        for (int e = 0; e < 4; ++e)
          bv[e] = *(float4*)&buf1[(j0+e)*SB + k4];
        #pragma unroll
        for (int d = 0; d < 4; ++d)
          #pragma unroll
          for (int e = 0; e < 4; ++e) {
            acc[d][e] = fmaf(av[d].x, bv[e].x, acc[d][e]);
            acc[d][e] = fmaf(av[d].y, bv[e].y, acc[d][e]);
            acc[d][e] = fmaf(av[d].z, bv[e].z, acc[d][e]);
            acc[d][e] = fmaf(av[d].w, bv[e].w, acc[d][e]);
          }
      }
      #pragma unroll
      for (int d = 0; d < 4; ++d) {
        float4 z4;
        z4.x = acc[d][0]; z4.y = acc[d][1]; z4.z = acc[d][2]; z4.w = acc[d][3];
        *(float4*)&buf0[(i0+d)*SB + j0] = z4;
      }
    }
    __syncthreads();
    // Z = U * C^T: Z[i][j] = sum_k U[i][k] * C[j][k]; offdiag -> global
    {
      float acc[4][4] = {};
      #pragma unroll
      for (int k4 = 0; k4 < 32; k4 += 4) {
        float4 av[4], bv[4];
        #pragma unroll
        for (int d = 0; d < 4; ++d)
          av[d] = *(float4*)&buf0[(i0+d)*SB + k4];
        #pragma unroll
        for (int e = 0; e < 4; ++e)
          bv[e] = *(const float4*)&Cw[(j0+e)*32 + k4];
        #pragma unroll
        for (int d = 0; d < 4; ++d)
          #pragma unroll
          for (int e = 0; e < 4; ++e) {
            acc[d][e] = fmaf(av[d].x, bv[e].x, acc[d][e]);
            acc[d][e] = fmaf(av[d].y, bv[e].y, acc[d][e]);
            acc[d][e] = fmaf(av[d].z, bv[e].z, acc[d][e]);
            acc[d][e] = fmaf(av[d].w, bv[e].w, acc[d][e]);
          }
      }
      float ss = 0.0f;
      float* outp = (w == 0) ? qo : ((w == 1) ? ko : vo);
      #pragma unroll
      for (int d = 0; d < 4; ++d) {
        #pragma unroll
        for (int e = 0; e < 4; ++e) {
          if (i0+d == j0+e) acc[d][e] = 0.0f;
          ss = fmaf(acc[d][e], acc[d][e], ss);
        }
        float4 z4;
        z4.x = acc[d][0]; z4.y = acc[d][1]; z4.z = acc[d][2]; z4.w = acc[d][3];
        *(float4*)&outp[(size_t)m*NF + (i0+d)*32 + j0] = z4;
      }
      if (w < 2) {
        #pragma unroll
        for (int off = 32; off > 0; off >>= 1)
          ss += __shfl_down(ss, off);
        if (t == 0)
          ((w == 0) ? q2 : k2)[m] = ss;
      }
      __syncthreads();   // Z reads of buf0 done before next U overwrite
    }
  }
}

// ---------------------------------------------------------------------------
// Kernel C1: G[b,j,i] = <kf[b,j], qf[b,i]> (K=1024), fused scores epilogue.
// R12: 128x128 tile, 256 threads, 8x8 micro-tile, K-major (transposed)
// staging -> inner loop is 4 broadcast ds_read_b128 vs 64 fma (compute-bound;
// old 64-tile/4x4 was 16 scalar ds_read per 32 fma -> LDS-bound, ~40% peak).
// Same K-accumulation order per element -> bit-identical output.
// ---------------------------------------------------------------------------
__global__ __launch_bounds__(256) void scores_kernel(
    const float* __restrict__ qf, const float* __restrict__ kf,
    const float* __restrict__ q2, const float* __restrict__ k2,
    float* __restrict__ P) {
  __shared__ float Ks[16][132];   // [k][j] transposed
  __shared__ float Qs[16][132];   // [k][i] transposed
  const int b = blockIdx.z;
  const int j0 = blockIdx.y * 128;
  const int i0 = blockIdx.x * 128;
  const int tx = threadIdx.x & 15, ty = threadIdx.x >> 4;  // i-group, j-group
  const int srow = threadIdx.x >> 1;        // staging row 0..127
  const int sk8  = (threadIdx.x & 1) * 8;   // staging k-offset 0 or 8
  float acc[8][8] = {};
  const float* kb = kf + (size_t)(b*NSQ + j0) * NF;
  const float* qb = qf + (size_t)(b*NSQ + i0) * NF;
  for (int f0 = 0; f0 < NF; f0 += 16) {
    float4 ka = *(const float4*)(kb + (size_t)srow*NF + f0 + sk8);
    float4 kb4 = *(const float4*)(kb + (size_t)srow*NF + f0 + sk8 + 4);
    float4 qa = *(const float4*)(qb + (size_t)srow*NF + f0 + sk8);
    float4 qb4 = *(const float4*)(qb + (size_t)srow*NF + f0 + sk8 + 4);
    __syncthreads();   // prev iteration's reads done before overwrite
    Ks[sk8+0][srow] = ka.x;  Ks[sk8+1][srow] = ka.y;
    Ks[sk8+2][srow] = ka.z;  Ks[sk8+3][srow] = ka.w;
    Ks[sk8+4][srow] = kb4.x; Ks[sk8+5][srow] = kb4.y;
    Ks[sk8+6][srow] = kb4.z; Ks[sk8+7][srow] = kb4.w;
    Qs[sk8+0][srow] = qa.x;  Qs[sk8+1][srow] = qa.y;
    Qs[sk8+2][srow] = qa.z;  Qs[sk8+3][srow] = qa.w;
    Qs[sk8+4][srow] = qb4.x; Qs[sk8+5][srow] = qb4.y;
    Qs[sk8+6][srow] = qb4.z; Qs[sk8+7][srow] = qb4.w;
    __syncthreads();
    #pragma unroll
    for (int kk = 0; kk < 16; ++kk) {
      float4 a0 = *(float4*)&Ks[kk][ty*8];
      float4 a1 = *(float4*)&Ks[kk][ty*8 + 4];
      float4 b0 = *(float4*)&Qs[kk][tx*8];
      float4 b1 = *(float4*)&Qs[kk][tx*8 + 4];
      float av[8] = {a0.x,a0.y,a0.z,a0.w,a1.x,a1.y,a1.z,a1.w};
      float bv[8] = {b0.x,b0.y,b0.z,b0.w,b1.x,b1.y,b1.z,b1.w};
      #pragma unroll
      for (int d = 0; d < 8; ++d)
        #pragma unroll
        for (int e = 0; e < 8; ++e)
          acc[d][e] = fmaf(av[d], bv[e], acc[d][e]);
    }
  }
  #pragma unroll
  for (int u = 0; u < 8; ++u) {
    int j = j0 + ty*8 + u;
    float kj = k2[b*NSQ + j];
    float* prow = P + (size_t)(b*NSQ + j)*NSQ + i0 + tx*8;
    #pragma unroll
    for (int vv = 0; vv < 8; ++vv) {
      int i = i0 + tx*8 + vv;
      float d2 = kj + q2[b*NSQ + i] - 2.0f * acc[u][vv];
      float e = sqrtf(fmaxf(d2, 1e-12f));
      prow[vv] = 1.0f / (1.0f + log1pf(e));
    }
  }
}

// ---------------------------------------------------------------------------
// Kernel C1b: softmax over j (axis -2) for each (b,i) column, in place.
// R11: 256 blocks x 512 threads, 1 block/CU, 32-load chains.
// ---------------------------------------------------------------------------
__global__ __launch_bounds__(512) void softmax_kernel(float* __restrict__ P) {
  __shared__ float red[16][32];
  const int b = blockIdx.x >> 4;
  const int i0 = (blockIdx.x & 15) * 32;
  const int il = threadIdx.x & 31;
  const int jg = threadIdx.x >> 5;   // 0..15
  float* base = P + (size_t)b*NSQ*NSQ + i0 + il;
  float mx = -1e30f;
  for (int j = jg*32; j < jg*32 + 32; ++j)
    mx = fmaxf(mx, base[(size_t)j*NSQ]);
  red[jg][il] = mx;
  __syncthreads();
  float cm = red[0][il];
  #pragma unroll
  for (int g = 1; g < 16; ++g) cm = fmaxf(cm, red[g][il]);
  __syncthreads();
  float ssum = 0.0f;
  for (int j = jg*32; j < jg*32 + 32; ++j)
    ssum += expf(base[(size_t)j*NSQ] - cm);
  red[jg][il] = ssum;
  __syncthreads();
  float tot = red[0][il];
  #pragma unroll
  for (int g = 1; g < 16; ++g) tot += red[g][il];
  float inv = 1.0f / tot;
  for (int j = jg*32; j < jg*32 + 32; ++j) {
    size_t o = (size_t)j*NSQ;
    base[o] = expf(base[o] - cm) * inv;
  }
}

// ---------------------------------------------------------------------------
// Kernel C2: out[b,c,f] = sum_a P[b,c,a] * vf[b,a,f]   (NN GEMM, K=512)
// R12: 128x128 tile, 256 threads, 8x8 micro, Ps staged K-major (transposed),
// Vs staged row-major (already K-major in f). Bit-identical accumulation.
// ---------------------------------------------------------------------------
__global__ __launch_bounds__(256) void out_gemm_kernel(
    const float* __restrict__ P, const float* __restrict__ vf,
    float* __restrict__ out) {
  __shared__ float Ps[16][132];   // [a][c] transposed
  __shared__ float Vs[16][132];   // [a][f]
  const int b = blockIdx.z;
  const int c0 = blockIdx.y * 128;
  const int f0 = blockIdx.x * 128;
  const int tx = threadIdx.x & 15, ty = threadIdx.x >> 4;  // f-group, c-group
  const int srow = threadIdx.x >> 1;        // P staging row (c) 0..127
  const int sk8  = (threadIdx.x & 1) * 8;   // P staging a-offset 0 or 8
  const int vrow = threadIdx.x >> 4;        // V staging row (a) 0..15
  const int vc8  = (threadIdx.x & 15) * 8;  // V staging f-offset
  float acc[8][8] = {};
  const float* Pb = P + (size_t)b * NSQ * NSQ;
  const float* Vb = vf + (size_t)b * NSQ * NF;
  for (int a0 = 0; a0 < NSQ; a0 += 16) {
    float4 pa = *(const float4*)(Pb + (size_t)(c0 + srow)*NSQ + a0 + sk8);
    float4 pb4 = *(const float4*)(Pb + (size_t)(c0 + srow)*NSQ + a0 + sk8 + 4);
    float4 va = *(const float4*)(Vb + (size_t)(a0 + vrow)*NF + f0 + vc8);
    float4 vb4 = *(const float4*)(Vb + (size_t)(a0 + vrow)*NF + f0 + vc8 + 4);
    __syncthreads();
    Ps[sk8+0][srow] = pa.x;  Ps[sk8+1][srow] = pa.y;
    Ps[sk8+2][srow] = pa.z;  Ps[sk8+3][srow] = pa.w;
    Ps[sk8+4][srow] = pb4.x; Ps[sk8+5][srow] = pb4.y;
    Ps[sk8+6][srow] = pb4.z; Ps[sk8+7][srow] = pb4.w;
    *(float4*)&Vs[vrow][vc8] = va;
    *(float4*)&Vs[vrow][vc8 + 4] = vb4;
    __syncthreads();
    #pragma unroll
    for (int kk = 0; kk < 16; ++kk) {
      float4 a0v = *(float4*)&Ps[kk][ty*8];
      float4 a1v = *(float4*)&Ps[kk][ty*8 + 4];
      float4 b0v = *(float4*)&Vs[kk][tx*8];
      float4 b1v = *(float4*)&Vs[kk][tx*8 + 4];
      float av[8] = {a0v.x,a0v.y,a0v.z,a0v.w,a1v.x,a1v.y,a1v.z,a1v.w};
      float bv[8] = {b0v.x,b0v.y,b0v.z,b0v.w,b1v.x,b1v.y,b1v.z,b1v.w};
      #pragma unroll
      for (int d = 0; d < 8; ++d)
        #pragma unroll
        for (int e = 0; e < 8; ++e)
          acc[d][e] = fmaf(av[d], bv[e], acc[d][e]);
    }
  }
  #pragma unroll
  for (int u = 0; u < 8; ++u) {
    float* orow = out + (size_t)(b*NSQ + c0 + ty*8 + u) * NF + f0 + tx*8;
    float4 o0; o0.x = acc[u][0]; o0.y = acc[u][1]; o0.z = acc[u][2]; o0.w = acc[u][3];
    float4 o1; o1.x = acc[u][4]; o1.y = acc[u][5]; o1.z = acc[u][6]; o1.w = acc[u][7];
    *(float4*)orow = o0;
    *(float4*)(orow + 4) = o1;
  }
}

extern "C" void kernel_launch(void* const* d_in, const int* in_sizes, int n_in,
                              void* d_out, int out_size, void* d_ws, size_t ws_size,
                              hipStream_t stream) {
  const float* x  = (const float*)d_in[0];
  const float* qw = (const float*)d_in[1];
  const float* kw = (const float*)d_in[2];
  const float* vw = (const float*)d_in[3];
  float* ws = (float*)d_ws;
  float* C  = ws;
  float* q  = ws + 3072;
  float* k  = q + (size_t)NMAT * NF;
  float* v  = k + (size_t)NMAT * NF;
  float* q2 = v + (size_t)NMAT * NF;
  float* k2 = q2 + NMAT;
  float* P  = k2 + NMAT;
  float* out = (float*)d_out;

  cayley_kernel<<<dim3(3), dim3(64), 0, stream>>>(qw, kw, vw, C);
  logm_qkv_kernel<<<dim3(NMAT), dim3(64), 0, stream>>>(x, C, q, k, v, q2, k2);
  scores_kernel<<<dim3(4, 4, NB), dim3(256), 0, stream>>>(q, k, q2, k2, P);
  softmax_kernel<<<dim3(NB * 16), dim3(512), 0, stream>>>(P);
  out_gemm_kernel<<<dim3(8, 4, NB), dim3(256), 0, stream>>>(P, v, out);
}